// Round 29
// baseline (325.622 us; speedup 1.0000x reference)
//
#include <hip/hip_runtime.h>
#include <math.h>

// Problem constants (B=1)
#define H_    16
#define DR_   64
#define HD_   128
#define D_    2048
#define SX_   2048
#define SY_   512
#define SZ_   2560
#define NQKV_ 6144          // 3*H*HD
#define EPS_  1e-6f
// 1/sqrt(192) * log2(e): scores arrive in log2 domain -> softmax uses bare v_exp_f32 (2^x)
#define ATTN_SCALE_L2E 0.10412035f
#define NS_   4             // KV splits (flash-decode)
#define SPL_  (SZ_ / NS_)   // 640 keys per split (multiple of 64)
#define QT_   (SZ_ / 128)   // 20 q-tiles

typedef __attribute__((ext_vector_type(8)))  short short8;   // bf16x8 MFMA frag (4 VGPR)
typedef __attribute__((ext_vector_type(16))) float f32x16;   // 32x32 MFMA accum

__device__ __forceinline__ unsigned short f2bf(float f) {
    unsigned u = __builtin_bit_cast(unsigned, f);
    u += 0x7FFF + ((u >> 16) & 1);          // RNE
    return (unsigned short)(u >> 16);
}
__device__ __forceinline__ unsigned pack2(float a, float b) {
    return (unsigned)f2bf(a) | ((unsigned)f2bf(b) << 16);
}
__device__ __forceinline__ float bf2f_lo(unsigned u) {
    return __builtin_bit_cast(float, u << 16);
}
__device__ __forceinline__ float bf2f_hi(unsigned u) {
    return __builtin_bit_cast(float, u & 0xffff0000u);
}

// RAW v_exp_f32 (2^x), no libm range-reduction fixup (r21/r22 lesson).
__device__ __forceinline__ float fexp2(float x) {
    return __builtin_amdgcn_exp2f(x);
}

__device__ __forceinline__ unsigned cvtpk_bf16(float lo, float hi) {
    unsigned r;
    asm volatile("v_cvt_pk_bf16_f32 %0, %1, %2" : "=v"(r) : "v"(lo), "v"(hi));
    return r;
}

// async global->LDS, 16B per lane (dest = wave-uniform base + lane*16)
__device__ __forceinline__ void gload16(const unsigned short* g, unsigned short* l) {
    __builtin_amdgcn_global_load_lds(
        (const __attribute__((address_space(1))) unsigned*)g,
        (__attribute__((address_space(3))) unsigned*)l, 16, 0, 0);
}

// T1: XCD-aware bijective remap (requires nwg % 8 == 0). Attention only (r12).
__device__ __forceinline__ int xcd_swz(int hw, int nwg) {
    return (hw & 7) * (nwg >> 3) + (hw >> 3);
}

// Build PV A/B fragment (16 keys) from 8 per-lane P values (C-reg order) via permlane32_swap.
__device__ __forceinline__ short8 mkfrag(const float* p) {
    unsigned a01 = cvtpk_bf16(p[0], p[1]);
    unsigned a23 = cvtpk_bf16(p[2], p[3]);
    unsigned a45 = cvtpk_bf16(p[4], p[5]);
    unsigned a67 = cvtpk_bf16(p[6], p[7]);
    asm volatile("v_permlane32_swap_b32 %0, %1" : "+v"(a01), "+v"(a45));
    asm volatile("v_permlane32_swap_b32 %0, %1" : "+v"(a23), "+v"(a67));
    union { unsigned u[4]; short8 s; } r;
    r.u[0] = a01; r.u[1] = a23; r.u[2] = a45; r.u[3] = a67;
    return r.s;
}

// ---------------- kernel 0+1 FUSED: weight cvt blocks ++ modulation-GEMV blocks -----------------
__global__ __launch_bounds__(256) void cvt_gemv_kernel(
    const float* __restrict__ s1, const float* __restrict__ s2, const float* __restrict__ s3,
    unsigned short* __restrict__ dst, int n1, int n2, int n3, int ncvt,
    const float* __restrict__ mod,
    const float* __restrict__ Wq, const float* __restrict__ bq,
    const float* __restrict__ Wkv, const float* __restrict__ bkv,
    float* __restrict__ mq, float* __restrict__ mkv)
{
    int bid = blockIdx.x, t = threadIdx.x;
    if (bid < ncvt) {
        int i = (bid * 256 + t) * 8;
        if (i >= n1 + n2 + n3) return;
        const float* src;
        if (i < n1)            src = s1 + i;
        else if (i < n1 + n2)  src = s2 + (i - n1);
        else                   src = s3 + (i - n1 - n2);
        float4 a = *(const float4*)(src);
        float4 b = *(const float4*)(src + 4);
        uint4 pk;
        pk.x = pack2(a.x, a.y); pk.y = pack2(a.z, a.w);
        pk.z = pack2(b.x, b.y); pk.w = pack2(b.z, b.w);
        *(uint4*)(dst + i) = pk;
    } else {
        int row = (bid - ncvt) * 4 + (t >> 6);
        int lane = t & 63;
        const float* W; const float* b; float* out; int r;
        if (row < NQKV_) { W = Wq;  b = bq;  out = mq;  r = row; }
        else             { W = Wkv; b = bkv; out = mkv; r = row - NQKV_; }
        const float* wr = W + (size_t)r * D_;
        float s = 0.f;
        for (int k = lane; k < D_; k += 64) s += wr[k] * mod[k];
#pragma unroll
        for (int m = 32; m >= 1; m >>= 1) s += __shfl_xor(s, m);
        if (lane == 0) out[r] = s + b[r];
    }
}

// ---------------- kernel 2: LayerNorm + modulation, bf16 out ----------------
__global__ __launch_bounds__(256) void ln_mod_kernel(
    const float* __restrict__ x, const float* __restrict__ y,
    const float* __restrict__ mq, const float* __restrict__ mkv,
    unsigned short* __restrict__ xm)
{
    __shared__ float red[8];
    int s = blockIdx.x, t = threadIdx.x;
    const float* src; const float* mv;
    if (s < SX_) { src = x + (size_t)s * D_;          mv = mq; }
    else         { src = y + (size_t)(s - SX_) * D_;  mv = mkv; }
    float a[8];
    *(float4*)&a[0] = *(const float4*)(src + t * 8);
    *(float4*)&a[4] = *(const float4*)(src + t * 8 + 4);
    float sum = 0.f, ssq = 0.f;
#pragma unroll
    for (int i = 0; i < 8; ++i) { sum += a[i]; ssq += a[i] * a[i]; }
#pragma unroll
    for (int m = 32; m >= 1; m >>= 1) { sum += __shfl_xor(sum, m); ssq += __shfl_xor(ssq, m); }
    if ((t & 63) == 0) { red[t >> 6] = sum; red[4 + (t >> 6)] = ssq; }
    __syncthreads();
    float tot  = red[0] + red[1] + red[2] + red[3];
    float totq = red[4] + red[5] + red[6] + red[7];
    float mean = tot * (1.f / (float)D_);
    float var  = totq * (1.f / (float)D_) - mean * mean;
    float inv  = rsqrtf(var + EPS_);
    float o[8];
#pragma unroll
    for (int i = 0; i < 8; ++i) {
        int c = t * 8 + i;
        float v = (a[i] - mean) * inv;
        o[i] = (1.f + mv[D_ + c]) * v + mv[c];
    }
    uint4 pk;
    pk.x = pack2(o[0], o[1]); pk.y = pack2(o[2], o[3]);
    pk.z = pack2(o[4], o[5]); pk.w = pack2(o[6], o[7]);
    *(uint4*)(xm + (size_t)s * D_ + t * 8) = pk;
}

// ---------------- kernel 3a: 8-wave 256x256 bf16 MFMA GEMM (QKV), T4 counted-vmcnt pipeline -----
// NEW (r29): BK=32, FOUR LDS buffers (4x16KB x2 = 128KB, same footprint), depth-2 pipeline.
// Prologue stages tiles 0,1. Iter kt: s_waitcnt vmcnt(4) (tile kt's 4 loads retired, in-order;
// tile kt+1's 4 stay IN FLIGHT across the barrier — T4/m218), barrier, stage tile kt+2 into
// buf[(kt+2)&3] (last read 2 barriers ago - safe), compute tile kt. Last iter drains vmcnt(0).
// Swizzle/fragments = r23's verified BK=32 code; only buffering depth + wait count changed.
__global__ __launch_bounds__(512, 2) void gemm8_bf16_kernel(
    const unsigned short* __restrict__ A,
    const unsigned short* __restrict__ Wx, const float* __restrict__ bx,
    const unsigned short* __restrict__ Wy, const float* __restrict__ by,
    unsigned short* __restrict__ C, int N)
{
    __shared__ __align__(16) unsigned short As[4][256 * 32];   // 4 x 16KB
    __shared__ __align__(16) unsigned short Bs[4][256 * 32];   // 4 x 16KB  (128KB total)
    int m0 = blockIdx.y * 256, n0 = blockIdx.x * 256;
    const unsigned short* W = (m0 < SX_) ? Wx : Wy;
    const float* bb = (m0 < SX_) ? bx : by;
    int t = threadIdx.x;                       // 0..511
    int wv = t >> 6, lane = t & 63, l31 = lane & 31, g = lane >> 5;
    int wr = wv >> 2, wc = wv & 3;             // 2 M-halves x 4 N-quarters
    // staging: chunk c = i*512 + t; row r = c>>2 (64B rows, 4 slots), slot sl = c&3,
    // source pre-swizzled with involution sl ^= (r>>1)&3 (linear gload_lds dest).
    int off[2];
#pragma unroll
    for (int i = 0; i < 2; ++i) {
        int c = i * 512 + t, r = c >> 2, sl = c & 3;
        off[i] = r * D_ + ((sl ^ ((r >> 1) & 3)) * 8);
    }
    const unsigned short* gA = A + (size_t)m0 * D_;
    const unsigned short* gW = W + (size_t)n0 * D_;
    int dstw = wv * 512;                       // shorts; instr i adds i*4096; lane*16B by HW
    f32x16 acc[4][2];
#pragma unroll
    for (int i = 0; i < 4; ++i)
#pragma unroll
        for (int j = 0; j < 2; ++j)
#pragma unroll
            for (int r = 0; r < 16; ++r) acc[i][j][r] = 0.f;
    int arow = wr * 128 + l31;                 // + i*32 : rows of A (B-operand of mfma)
    int brow = wc * 64 + l31;                  // + j*32 : rows of W (A-operand of mfma)
    int a3 = (arow >> 1) & 3, w3 = (brow >> 1) & 3;   // (row+32i)>>1 &3 is frag-invariant

    // prologue: stage K-tiles 0 and 1 (4 loads each per thread)
#pragma unroll
    for (int i = 0; i < 2; ++i) gload16(gA + off[i],      &As[0][i * 4096 + dstw]);
#pragma unroll
    for (int i = 0; i < 2; ++i) gload16(gW + off[i],      &Bs[0][i * 4096 + dstw]);
#pragma unroll
    for (int i = 0; i < 2; ++i) gload16(gA + 32 + off[i], &As[1][i * 4096 + dstw]);
#pragma unroll
    for (int i = 0; i < 2; ++i) gload16(gW + 32 + off[i], &Bs[1][i * 4096 + dstw]);

    const int NT = D_ / 32;                    // 64 K-tiles
    for (int kt = 0; kt < NT; ++kt) {
        int cur = kt & 3;
        // counted wait: tile kt retired (oldest 4), tile kt+1's loads remain in flight
        if (kt + 1 < NT) asm volatile("s_waitcnt vmcnt(4)" ::: "memory");
        else             asm volatile("s_waitcnt vmcnt(0)" ::: "memory");
        __builtin_amdgcn_s_barrier();          // all waves' tile-kt loads landed
        if (kt + 2 < NT) {                     // stage tile kt+2 (buf last read 2 barriers ago)
            int nb = (kt + 2) & 3, k2 = (kt + 2) * 32;
#pragma unroll
            for (int i = 0; i < 2; ++i) gload16(gA + k2 + off[i], &As[nb][i * 4096 + dstw]);
#pragma unroll
            for (int i = 0; i < 2; ++i) gload16(gW + k2 + off[i], &Bs[nb][i * 4096 + dstw]);
        }
#pragma unroll
        for (int ks = 0; ks < 2; ++ks) {       // 2 k-slices of 16
            int slot = ks * 2 + g;
            short8 af[4], bf[2];
#pragma unroll
            for (int i = 0; i < 4; ++i)
                af[i] = *(const short8*)&As[cur][(arow + i * 32) * 32 + ((slot ^ a3) * 8)];
#pragma unroll
            for (int j = 0; j < 2; ++j)
                bf[j] = *(const short8*)&Bs[cur][(brow + j * 32) * 32 + ((slot ^ w3) * 8)];
#pragma unroll
            for (int i = 0; i < 4; ++i)
#pragma unroll
                for (int j = 0; j < 2; ++j)
                    acc[i][j] = __builtin_amdgcn_mfma_f32_32x32x16_bf16(bf[j], af[i], acc[i][j], 0, 0, 0);
        }
    }

#pragma unroll
    for (int i = 0; i < 4; ++i) {
        int row = m0 + wr * 128 + i * 32 + l31;
#pragma unroll
        for (int j = 0; j < 2; ++j)
#pragma unroll
            for (int q = 0; q < 4; ++q) {
                int n = n0 + wc * 64 + j * 32 + q * 8 + 4 * g;
                float o0 = acc[i][j][q * 4 + 0] + bb[n + 0];
                float o1 = acc[i][j][q * 4 + 1] + bb[n + 1];
                float o2 = acc[i][j][q * 4 + 2] + bb[n + 2];
                float o3 = acc[i][j][q * 4 + 3] + bb[n + 3];
                *(uint2*)(C + (size_t)row * N + n) = make_uint2(pack2(o0, o1), pack2(o2, o3));
            }
    }
}

// ---------------- kernel 3b: 2-phase 128x128 GEMM (out-proj, f32+gate+residual epilogue) --------
__global__ __launch_bounds__(256) void gemm_bf16_kernel(
    const unsigned short* __restrict__ A,
    const unsigned short* __restrict__ Wx, const float* __restrict__ bx,
    const unsigned short* __restrict__ Wy, const float* __restrict__ by,
    void* __restrict__ Cout, int N,
    const float* __restrict__ gx, const float* __restrict__ gy,
    const float* __restrict__ rx, const float* __restrict__ ry,
    int mode)
{
    __shared__ __align__(16) unsigned short As[2][128 * 32];
    __shared__ __align__(16) unsigned short Bs[2][128 * 32];
    int m0 = blockIdx.y * 128, n0 = blockIdx.x * 128;
    const unsigned short* W = (m0 < SX_) ? Wx : Wy;
    const float* bb = (m0 < SX_) ? bx : by;
    int t = threadIdx.x;
    int wv = t >> 6, lane = t & 63, l31 = lane & 31, g = lane >> 5;
    int wr = wv >> 1, wc = wv & 1;
    int srow = t >> 2, ssl = t & 3;
    const unsigned short* gA = A + (size_t)(m0 + srow) * D_ + ((ssl ^ ((srow >> 1) & 3)) * 8);
    const unsigned short* gW = W + (size_t)(n0 + srow) * D_ + ((ssl ^ ((srow >> 1) & 3)) * 8);
    f32x16 acc[2][2];
#pragma unroll
    for (int i = 0; i < 2; ++i)
#pragma unroll
        for (int j = 0; j < 2; ++j)
#pragma unroll
            for (int r = 0; r < 16; ++r) acc[i][j][r] = 0.f;
    int arow = wr * 64 + l31;
    int wrow = wc * 64 + l31;
    int a3 = (arow >> 1) & 3, w3 = (wrow >> 1) & 3;

    gload16(gA,            &As[0][wv * 512]);
    gload16(gA + 64 * D_,  &As[0][2048 + wv * 512]);
    gload16(gW,            &Bs[0][wv * 512]);
    gload16(gW + 64 * D_,  &Bs[0][2048 + wv * 512]);
    __syncthreads();

    for (int k0 = 0; k0 < D_; k0 += 32) {
        int cur = (k0 >> 5) & 1;
        if (k0 + 32 < D_) {
            int nb = cur ^ 1;
            gload16(gA + k0 + 32,           &As[nb][wv * 512]);
            gload16(gA + 64 * D_ + k0 + 32, &As[nb][2048 + wv * 512]);
            gload16(gW + k0 + 32,           &Bs[nb][wv * 512]);
            gload16(gW + 64 * D_ + k0 + 32, &Bs[nb][2048 + wv * 512]);
        }
#pragma unroll
        for (int kk = 0; kk < 2; ++kk) {
            int slot = kk * 2 + g;
            short8 af[2], wf[2];
#pragma unroll
            for (int i = 0; i < 2; ++i) {
                af[i] = *(const short8*)&As[cur][(arow + i * 32) * 32 + ((slot ^ a3) * 8)];
                wf[i] = *(const short8*)&Bs[cur][(wrow + i * 32) * 32 + ((slot ^ w3) * 8)];
            }
#pragma unroll
            for (int i = 0; i < 2; ++i)
#pragma unroll
                for (int j = 0; j < 2; ++j)
                    acc[i][j] = __builtin_amdgcn_mfma_f32_32x32x16_bf16(wf[j], af[i], acc[i][j], 0, 0, 0);
        }
        __syncthreads();
    }

#pragma unroll
    for (int i = 0; i < 2; ++i) {
        int row = m0 + wr * 64 + i * 32 + l31;
        if (mode == 0) {
            unsigned short* C = (unsigned short*)Cout;
#pragma unroll
            for (int j = 0; j < 2; ++j)
#pragma unroll
                for (int q = 0; q < 4; ++q) {
                    int n = n0 + wc * 64 + j * 32 + q * 8 + 4 * g;
                    float o0 = acc[i][j][q * 4 + 0] + bb[n + 0];
                    float o1 = acc[i][j][q * 4 + 1] + bb[n + 1];
                    float o2 = acc[i][j][q * 4 + 2] + bb[n + 2];
                    float o3 = acc[i][j][q * 4 + 3] + bb[n + 3];
                    *(uint2*)(C + (size_t)row * N + n) = make_uint2(pack2(o0, o1), pack2(o2, o3));
                }
        } else {
            float* C = (float*)Cout;
            const float* gt = (row < SX_) ? gx : gy;
            const float* rr = (row < SX_) ? rx + (size_t)row * N : ry + (size_t)(row - SX_) * N;
#pragma unroll
            for (int j = 0; j < 2; ++j)
#pragma unroll
                for (int q = 0; q < 4; ++q) {
                    int n = n0 + wc * 64 + j * 32 + q * 8 + 4 * g;
                    float4 o;
                    o.x = (acc[i][j][q * 4 + 0] + bb[n + 0]) * gt[n + 0] + rr[n + 0];
                    o.y = (acc[i][j][q * 4 + 1] + bb[n + 1]) * gt[n + 1] + rr[n + 1];
                    o.z = (acc[i][j][q * 4 + 2] + bb[n + 2]) * gt[n + 2] + rr[n + 2];
                    o.w = (acc[i][j][q * 4 + 3] + bb[n + 3]) * gt[n + 3] + rr[n + 3];
                    *(float4*)(C + (size_t)row * N + n) = o;
                }
        }
    }
}

// ---------------- kernel 4+4b FUSED: RMS+RoPE blocks ++ V-transpose blocks ----------------------
__global__ __launch_bounds__(256) void qkvt_vtrans_kernel(
    const unsigned short* __restrict__ qkvb,
    const float* __restrict__ fx, const float* __restrict__ fy,
    const float* __restrict__ wq, const float* __restrict__ wk,
    unsigned short* __restrict__ qh, unsigned short* __restrict__ kh,
    unsigned short* __restrict__ vt, int nqkvt)
{
    __shared__ __align__(16) unsigned short T[64][72];
    int bid = blockIdx.x, t = threadIdx.x;
    if (bid < nqkvt) {
        int gid = bid * 4 + (t >> 6);
        int lane = t & 63;
        int s = gid >> 4;
        int h = gid & 15;
        const unsigned short* base = qkvb + (size_t)s * NQKV_ + h * HD_;
        int d = lane * 2;
        unsigned qu = *(const unsigned*)(base + d);
        unsigned ku = *(const unsigned*)(base + 2048 + d);
        float qx = bf2f_lo(qu), qy = bf2f_hi(qu);
        float kx = bf2f_lo(ku), ky = bf2f_hi(ku);
        float sq = qx * qx + qy * qy;
        float sk = kx * kx + ky * ky;
#pragma unroll
        for (int m = 32; m >= 1; m >>= 1) { sq += __shfl_xor(sq, m); sk += __shfl_xor(sk, m); }
        float qs = rsqrtf(sq * (1.f / 128.f) + EPS_) * ATTN_SCALE_L2E;
        float ks = rsqrtf(sk * (1.f / 128.f) + EPS_);
        float q0 = qx * qs * wq[d], q1 = qy * qs * wq[d + 1];
        float k0 = kx * ks * wk[d], k1 = ky * ks * wk[d + 1];
        if (lane < 32) {
            const float* f = (s < SX_) ? fx + (size_t)s * DR_ + d
                                       : fy + (size_t)(s - SX_) * DR_ + d;
            float cs = f[0], sn = f[1];
            float o0 = q0 * cs - q1 * sn, o1 = q0 * sn + q1 * cs;
            q0 = o0; q1 = o1;
            o0 = k0 * cs - k1 * sn; o1 = k0 * sn + k1 * cs;
            k0 = o0; k1 = o1;
        }
        size_t off = ((size_t)h * SZ_ + s) * HD_ + d;
        *(unsigned*)(qh + off) = pack2(q0, q1);
        *(unsigned*)(kh + off) = pack2(k0, k1);
    } else {
        int lid = bid - nqkvt;
        int s0 = (lid % 40) * 64;
        int d0 = ((lid / 40) & 1) * 64;
        int h  = lid / 80;
        int r = t >> 2, c = (t & 3) * 16;
        const unsigned short* src = qkvb + (size_t)(s0 + r) * NQKV_ + 4096 + h * HD_ + d0 + c;
        *(short8*)&T[r][c]     = *(const short8*)(src);
        *(short8*)&T[r][c + 8] = *(const short8*)(src + 8);
        __syncthreads();
        unsigned short o16[16];
#pragma unroll
        for (int i = 0; i < 16; ++i) o16[i] = T[c + i][r];
        unsigned short* dst = vt + ((size_t)h * HD_ + d0 + r) * SZ_ + s0 + c;
        *(short8*)dst       = *(short8*)&o16[0];
        *(short8*)(dst + 8) = *(short8*)&o16[8];
    }
}

// ---------------- kernel 5: bf16 MFMA flash attention, KV-split + dbuf gload_lds + T1 ------------
__global__ __launch_bounds__(256) void attn_mfma_kernel(
    const unsigned short* __restrict__ qh, const unsigned short* __restrict__ kh,
    const unsigned short* __restrict__ vt,
    unsigned short* __restrict__ Opart, float* __restrict__ mpart, float* __restrict__ lpart)
{
    __shared__ __align__(16) short Ks[2][64 * 128];   // [key][d], 256B rows, slot swizzled
    __shared__ __align__(16) short Vs[2][128 * 64];   // [d][key], 128B rows, slot swizzled
    int hw = (blockIdx.z * gridDim.y + blockIdx.y) * gridDim.x + blockIdx.x;
    int lg = xcd_swz(hw, QT_ * H_ * NS_);             // 1280 % 8 == 0
    int qt    = lg % QT_;
    int hs    = lg / QT_;
    int h     = hs % H_;
    int split = hs / H_;
    int t = threadIdx.x;
    int wv = t >> 6, lane = t & 63;
    int l31 = lane & 31, g = lane >> 5;
    int bq = qt * 128 + wv * 32;
    const unsigned short* kbase = kh + (size_t)h * SZ_ * HD_;
    const unsigned short* vbase = vt + (size_t)h * HD_ * SZ_;

    int koff[4], voff[4];
#pragma unroll
    for (int i = 0; i < 4; ++i) {
        int idx = i * 256 + t;
        int r = idx >> 4, sl = idx & 15;
        koff[i] = r * HD_ + (((sl & 8) | ((sl ^ (r & 7)) & 7)) * 8);
        int r2 = idx >> 3, sl2 = idx & 7;
        voff[i] = r2 * SZ_ + ((sl2 ^ (r2 & 7)) * 8);
    }
    int ldsOff = wv * 512;

    short8 qf[8];
    {
        const unsigned short* qb = qh + ((size_t)h * SZ_ + bq + l31) * HD_ + g * 8;
#pragma unroll
        for (int s = 0; s < 8; ++s) qf[s] = *(const short8*)(qb + s * 16);
    }

    f32x16 o[4];
#pragma unroll
    for (int db = 0; db < 4; ++db)
#pragma unroll
        for (int r = 0; r < 16; ++r) o[db][r] = 0.f;
    float mreg = -INFINITY, lreg = 0.f;
    bool qY = (bq >= SX_);
    int sw7 = l31 & 7;
    int ts0 = split * SPL_;
    const int NT = SPL_ / 64;   // 10

#pragma unroll
    for (int i = 0; i < 4; ++i)
        gload16(kbase + (size_t)ts0 * HD_ + koff[i], (unsigned short*)&Ks[0][0] + i * 2048 + ldsOff);
#pragma unroll
    for (int i = 0; i < 4; ++i)
        gload16(vbase + ts0 + voff[i], (unsigned short*)&Vs[0][0] + i * 2048 + ldsOff);
    __syncthreads();

    for (int it = 0; it < NT; ++it) {
        int t0 = ts0 + it * 64;
        int cur = it & 1;
        if (it + 1 < NT) {
            int nb = cur ^ 1;
            const unsigned short* kn = kbase + (size_t)(t0 + 64) * HD_;
            const unsigned short* vn = vbase + (t0 + 64);
#pragma unroll
            for (int i = 0; i < 4; ++i)
                gload16(kn + koff[i], (unsigned short*)&Ks[nb][0] + i * 2048 + ldsOff);
#pragma unroll
            for (int i = 0; i < 4; ++i)
                gload16(vn + voff[i], (unsigned short*)&Vs[nb][0] + i * 2048 + ldsOff);
        }

        bool same = (qY == (t0 >= SX_));
        f32x16 sc0, sc1;
#pragma unroll
        for (int r = 0; r < 16; ++r) { sc0[r] = 0.f; sc1[r] = 0.f; }
        const short* Krow0 = &Ks[cur][0] + l31 * 128;
        const short* Krow1 = &Ks[cur][0] + (l31 + 32) * 128;
        __builtin_amdgcn_s_setprio(1);
#pragma unroll
        for (int s = 4; s < 8; ++s) {
            int slot = 2 * s + g;
            int sl = (slot & 8) | ((slot ^ sw7) & 7);
            sc0 = __builtin_amdgcn_mfma_f32_32x32x16_bf16(*(const short8*)(Krow0 + sl * 8), qf[s], sc0, 0, 0, 0);
            sc1 = __builtin_amdgcn_mfma_f32_32x32x16_bf16(*(const short8*)(Krow1 + sl * 8), qf[s], sc1, 0, 0, 0);
        }
        if (same) {
#pragma unroll
            for (int s = 0; s < 4; ++s) {
                int slot = 2 * s + g;
                int sl = (slot & 8) | ((slot ^ sw7) & 7);
                sc0 = __builtin_amdgcn_mfma_f32_32x32x16_bf16(*(const short8*)(Krow0 + sl * 8), qf[s], sc0, 0, 0, 0);
                sc1 = __builtin_amdgcn_mfma_f32_32x32x16_bf16(*(const short8*)(Krow1 + sl * 8), qf[s], sc1, 0, 0, 0);
            }
        }
        __builtin_amdgcn_s_setprio(0);

        // ---- balanced-tree max (depth 6) ----
        float mx8[8];
#pragma unroll
        for (int r = 0; r < 8; ++r)
            mx8[r] = fmaxf(fmaxf(sc0[r], sc0[r + 8]), fmaxf(sc1[r], sc1[r + 8]));
        float mx40 = fmaxf(mx8[0], mx8[4]), mx41 = fmaxf(mx8[1], mx8[5]);
        float mx42 = fmaxf(mx8[2], mx8[6]), mx43 = fmaxf(mx8[3], mx8[7]);
        float pm = fmaxf(fmaxf(mx40, mx41), fmaxf(mx42, mx43));
        pm = fmaxf(pm, __shfl_xor(pm, 32));
        float mnew = fmaxf(mreg, pm);
        float corr = fexp2(mreg - mnew);       // raw v_exp_f32
        mreg = mnew;
        float pp0[16], pp1[16];
#pragma unroll
        for (int r = 0; r < 16; ++r) {
            pp0[r] = fexp2(sc0[r] - mnew);
            pp1[r] = fexp2(sc1[r] - mnew);
        }
        // ---- balanced-tree sum (depth 6) ----
        float s8[8];
#pragma unroll
        for (int r = 0; r < 8; ++r)
            s8[r] = (pp0[r] + pp0[r + 8]) + (pp1[r] + pp1[r + 8]);
        float s40 = s8[0] + s8[4], s41 = s8[1] + s8[5];
        float s42 = s8[2] + s8[6], s43 = s8[3] + s8[7];
        float rs = (s40 + s41) + (s42 + s43);
        rs += __shfl_xor(rs, 32);
        lreg = lreg * corr + rs;
#pragma unroll
        for (int db = 0; db < 4; ++db)
#pragma unroll
            for (int r = 0; r < 16; ++r) o[db][r] *= corr;

        short8 pa0 = mkfrag(&pp0[0]), pa1 = mkfrag(&pp0[8]);
        short8 pa2 = mkfrag(&pp1[0]), pa3 = mkfrag(&pp1[8]);
        const short* Vb = &Vs[cur][0];
        __builtin_amdgcn_s_setprio(1);
#pragma unroll
        for (int ks = 0; ks < 4; ++ks) {
            short8 pf = (ks == 0) ? pa0 : (ks == 1) ? pa1 : (ks == 2) ? pa2 : pa3;
#pragma unroll
            for (int db = 0; db < 4; ++db) {
                int row = db * 32 + l31;
                int sl = (2 * ks + g) ^ (l31 & 7);
                const short8 vf = *(const short8*)(Vb + row * 64 + sl * 8);
                o[db] = __builtin_amdgcn_mfma_f32_32x32x16_bf16(vf, pf, o[db], 0, 0, 0);
            }
        }
        __builtin_amdgcn_s_setprio(0);
        __syncthreads();
    }

    // write unnormalized partial — acc regs q*4..q*4+3 map to contiguous d (C/D layout),
    // so pack 4 bf16 into one uint2 store.
    int basep = ((split * QT_ + qt) * H_ + h) * 128 + wv * 32 + l31;
    unsigned short* op = Opart + (size_t)basep * 128;
#pragma unroll
    for (int db = 0; db < 4; ++db)
#pragma unroll
        for (int q = 0; q < 4; ++q) {
            int d = db * 32 + q * 8 + 4 * g;
            *(uint2*)(op + d) = make_uint2(
                pack2(o[db][q * 4 + 0], o[db][q * 4 + 1]),
                pack2(o[db][q * 4 + 2], o[db][q * 4 + 3]));
        }
    if (g == 0) { mpart[basep] = mreg; lpart[basep] = lreg; }
}

// ---------------- kernel 5b: combine NS_ partials -> bf16 z (m in log2 domain) ------------------
__global__ __launch_bounds__(256) void attn_combine_kernel(
    const unsigned short* __restrict__ Opart,
    const float* __restrict__ mpart, const float* __restrict__ lpart,
    unsigned short* __restrict__ z)
{
    int t = threadIdx.x;
    int gid = blockIdx.x * 4 + (t >> 6);
    int lane = t & 63;
    int h = gid & 15;
    int r = gid >> 4;
    int qtile = r >> 7, qi = r & 127;
    int pidx[NS_];
    float m[NS_];
    float mx = -INFINITY;
#pragma unroll
    for (int s = 0; s < NS_; ++s) {
        pidx[s] = ((s * QT_ + qtile) * H_ + h) * 128 + qi;
        m[s] = mpart[pidx[s]];
        mx = fmaxf(mx, m[s]);
    }
    float L = 0.f;
    float w[NS_];
#pragma unroll
    for (int s = 0; s < NS_; ++s) {
        w[s] = fexp2(m[s] - mx);               // log2 domain, raw v_exp_f32
        L += w[s] * lpart[pidx[s]];
    }
    float invL = 1.f / L;
    int d = lane * 2;
    float a0 = 0.f, a1 = 0.f;
#pragma unroll
    for (int s = 0; s < NS_; ++s) {
        unsigned u = *(const unsigned*)(Opart + (size_t)pidx[s] * 128 + d);
        a0 += w[s] * bf2f_lo(u);
        a1 += w[s] * bf2f_hi(u);
    }
    *(unsigned*)(z + (size_t)r * D_ + h * HD_ + d) = pack2(a0 * invL, a1 * invL);
}

extern "C" void kernel_launch(void* const* d_in, const int* in_sizes, int n_in,
                              void* d_out, int out_size, void* d_ws, size_t ws_size,
                              hipStream_t stream) {
    const float* x    = (const float*)d_in[0];
    const float* y    = (const float*)d_in[1];
    const float* mod  = (const float*)d_in[2];
    const float* fx   = (const float*)d_in[3];
    const float* fy   = (const float*)d_in[4];
    const float* Wqx  = (const float*)d_in[7];
    const float* bqx  = (const float*)d_in[8];
    const float* Wqy  = (const float*)d_in[9];
    const float* bqy  = (const float*)d_in[10];
    const float* Wout = (const float*)d_in[11];
    const float* bout = (const float*)d_in[12];
    const float* wq   = (const float*)d_in[13];
    const float* wk   = (const float*)d_in[14];
    const float* Wmq  = (const float*)d_in[15];
    const float* bmq  = (const float*)d_in[16];
    const float* Wmk  = (const float*)d_in[17];
    const float* bmk  = (const float*)d_in[18];

    // workspace layout — total ≈ 142.8 MB (vh slot unused, layout kept stable)
    float* mq   = (float*)d_ws;                              // 6144
    float* mkv  = mq + NQKV_;                                // 6144
    unsigned short* xm   = (unsigned short*)(mkv + NQKV_);   // SZ*D bf16 (later: z)
    unsigned short* qkvb = xm + (size_t)SZ_ * D_;            // SZ*6144 bf16 (later: m/l partials)
    unsigned short* qh   = qkvb + (size_t)SZ_ * NQKV_;       // H*SZ*HD bf16 each
    unsigned short* kh   = qh + (size_t)H_ * SZ_ * HD_;
    unsigned short* vh   = kh + (size_t)H_ * SZ_ * HD_;      // (unused)
    unsigned short* vt   = vh + (size_t)H_ * SZ_ * HD_;
    unsigned short* wqxb = vt + (size_t)H_ * SZ_ * HD_;      // 6144*2048 bf16 (later: O~ partials)
    unsigned short* wqyb = wqxb + (size_t)NQKV_ * D_;
    unsigned short* wob  = wqyb + (size_t)NQKV_ * D_;        // 2048*2048 bf16
    unsigned short* z    = xm;                               // alias: xm dead after QKV GEMM
    unsigned short* Opart = wqxb;
    float* mpart = (float*)qkvb;
    float* lpart = mpart + NS_ * QT_ * H_ * 128;
    float* out  = (float*)d_out;

    const int n1 = NQKV_ * D_, n3 = D_ * D_;
    const int ncvt = (2 * n1 + n3) / 2048;                   // 14336
    const int ngemv = 2 * NQKV_ / 4;                         // 3072
    hipLaunchKernelGGL(cvt_gemv_kernel, dim3(ncvt + ngemv), dim3(256), 0, stream,
                       Wqx, Wqy, Wout, wqxb, n1, n1, n3, ncvt,
                       mod, Wmq, bmq, Wmk, bmk, mq, mkv);
    hipLaunchKernelGGL(ln_mod_kernel, dim3(SZ_), dim3(256), 0, stream,
                       x, y, mq, mkv, xm);
    hipLaunchKernelGGL(gemm8_bf16_kernel, dim3(NQKV_ / 256, SZ_ / 256), dim3(512), 0, stream,
                       xm, wqxb, bqx, wqyb, bqy, qkvb, NQKV_);
    const int nqkvt = SZ_ * H_ / 4;                          // 10240
    const int nvt = (SZ_ / 64) * (HD_ / 64) * H_;            // 1280
    hipLaunchKernelGGL(qkvt_vtrans_kernel, dim3(nqkvt + nvt), dim3(256), 0, stream,
                       qkvb, fx, fy, wq, wk, qh, kh, vt, nqkvt);
    hipLaunchKernelGGL(attn_mfma_kernel, dim3(QT_, H_, NS_), dim3(256), 0, stream,
                       qh, kh, vt, Opart, mpart, lpart);
    hipLaunchKernelGGL(attn_combine_kernel, dim3(SZ_ * H_ / 4), dim3(256), 0, stream,
                       Opart, mpart, lpart, z);
    hipLaunchKernelGGL(gemm_bf16_kernel, dim3(D_ / 128, SZ_ / 128), dim3(256), 0, stream,
                       z, wob, bout, wob, bout, (void*)out, D_,
                       mq + 2 * D_, mkv + 2 * D_, x, y, 1);
}

// Round 30
// 309.292 us; speedup vs baseline: 1.0528x; 1.0528x over previous
//
#include <hip/hip_runtime.h>
#include <math.h>

// Problem constants (B=1)
#define H_    16
#define DR_   64
#define HD_   128
#define D_    2048
#define SX_   2048
#define SY_   512
#define SZ_   2560
#define NQKV_ 6144          // 3*H*HD
#define EPS_  1e-6f
// 1/sqrt(192) * log2(e): scores arrive in log2 domain -> softmax uses bare v_exp_f32 (2^x)
#define ATTN_SCALE_L2E 0.10412035f
#define NS_   4             // KV splits (flash-decode)
#define SPL_  (SZ_ / NS_)   // 640 keys per split (multiple of 64)
#define QT_   (SZ_ / 128)   // 20 q-tiles

typedef __attribute__((ext_vector_type(8)))  short short8;   // bf16x8 MFMA frag (4 VGPR)
typedef __attribute__((ext_vector_type(16))) float f32x16;   // 32x32 MFMA accum

__device__ __forceinline__ unsigned short f2bf(float f) {
    unsigned u = __builtin_bit_cast(unsigned, f);
    u += 0x7FFF + ((u >> 16) & 1);          // RNE
    return (unsigned short)(u >> 16);
}
__device__ __forceinline__ unsigned pack2(float a, float b) {
    return (unsigned)f2bf(a) | ((unsigned)f2bf(b) << 16);
}
__device__ __forceinline__ float bf2f_lo(unsigned u) {
    return __builtin_bit_cast(float, u << 16);
}
__device__ __forceinline__ float bf2f_hi(unsigned u) {
    return __builtin_bit_cast(float, u & 0xffff0000u);
}

// RAW v_exp_f32 (2^x), no libm range-reduction fixup (r21/r22 lesson).
__device__ __forceinline__ float fexp2(float x) {
    return __builtin_amdgcn_exp2f(x);
}

__device__ __forceinline__ unsigned cvtpk_bf16(float lo, float hi) {
    unsigned r;
    asm volatile("v_cvt_pk_bf16_f32 %0, %1, %2" : "=v"(r) : "v"(lo), "v"(hi));
    return r;
}

// async global->LDS, 16B per lane (dest = wave-uniform base + lane*16)
__device__ __forceinline__ void gload16(const unsigned short* g, unsigned short* l) {
    __builtin_amdgcn_global_load_lds(
        (const __attribute__((address_space(1))) unsigned*)g,
        (__attribute__((address_space(3))) unsigned*)l, 16, 0, 0);
}

// T1: XCD-aware bijective remap (requires nwg % 8 == 0). Attention only (r12).
__device__ __forceinline__ int xcd_swz(int hw, int nwg) {
    return (hw & 7) * (nwg >> 3) + (hw >> 3);
}

// Build PV A/B fragment (16 keys) from 8 per-lane P values (C-reg order) via permlane32_swap.
__device__ __forceinline__ short8 mkfrag(const float* p) {
    unsigned a01 = cvtpk_bf16(p[0], p[1]);
    unsigned a23 = cvtpk_bf16(p[2], p[3]);
    unsigned a45 = cvtpk_bf16(p[4], p[5]);
    unsigned a67 = cvtpk_bf16(p[6], p[7]);
    asm volatile("v_permlane32_swap_b32 %0, %1" : "+v"(a01), "+v"(a45));
    asm volatile("v_permlane32_swap_b32 %0, %1" : "+v"(a23), "+v"(a67));
    union { unsigned u[4]; short8 s; } r;
    r.u[0] = a01; r.u[1] = a23; r.u[2] = a45; r.u[3] = a67;
    return r.s;
}

// ---------------- kernel 0+1 FUSED: weight cvt blocks ++ modulation-GEMV blocks -----------------
__global__ __launch_bounds__(256) void cvt_gemv_kernel(
    const float* __restrict__ s1, const float* __restrict__ s2, const float* __restrict__ s3,
    unsigned short* __restrict__ dst, int n1, int n2, int n3, int ncvt,
    const float* __restrict__ mod,
    const float* __restrict__ Wq, const float* __restrict__ bq,
    const float* __restrict__ Wkv, const float* __restrict__ bkv,
    float* __restrict__ mq, float* __restrict__ mkv)
{
    int bid = blockIdx.x, t = threadIdx.x;
    if (bid < ncvt) {
        int i = (bid * 256 + t) * 8;
        if (i >= n1 + n2 + n3) return;
        const float* src;
        if (i < n1)            src = s1 + i;
        else if (i < n1 + n2)  src = s2 + (i - n1);
        else                   src = s3 + (i - n1 - n2);
        float4 a = *(const float4*)(src);
        float4 b = *(const float4*)(src + 4);
        uint4 pk;
        pk.x = pack2(a.x, a.y); pk.y = pack2(a.z, a.w);
        pk.z = pack2(b.x, b.y); pk.w = pack2(b.z, b.w);
        *(uint4*)(dst + i) = pk;
    } else {
        int row = (bid - ncvt) * 4 + (t >> 6);
        int lane = t & 63;
        const float* W; const float* b; float* out; int r;
        if (row < NQKV_) { W = Wq;  b = bq;  out = mq;  r = row; }
        else             { W = Wkv; b = bkv; out = mkv; r = row - NQKV_; }
        const float* wr = W + (size_t)r * D_;
        float s = 0.f;
        for (int k = lane; k < D_; k += 64) s += wr[k] * mod[k];
#pragma unroll
        for (int m = 32; m >= 1; m >>= 1) s += __shfl_xor(s, m);
        if (lane == 0) out[r] = s + b[r];
    }
}

// ---------------- kernel 2: LayerNorm + modulation, bf16 out ----------------
__global__ __launch_bounds__(256) void ln_mod_kernel(
    const float* __restrict__ x, const float* __restrict__ y,
    const float* __restrict__ mq, const float* __restrict__ mkv,
    unsigned short* __restrict__ xm)
{
    __shared__ float red[8];
    int s = blockIdx.x, t = threadIdx.x;
    const float* src; const float* mv;
    if (s < SX_) { src = x + (size_t)s * D_;          mv = mq; }
    else         { src = y + (size_t)(s - SX_) * D_;  mv = mkv; }
    float a[8];
    *(float4*)&a[0] = *(const float4*)(src + t * 8);
    *(float4*)&a[4] = *(const float4*)(src + t * 8 + 4);
    float sum = 0.f, ssq = 0.f;
#pragma unroll
    for (int i = 0; i < 8; ++i) { sum += a[i]; ssq += a[i] * a[i]; }
#pragma unroll
    for (int m = 32; m >= 1; m >>= 1) { sum += __shfl_xor(sum, m); ssq += __shfl_xor(ssq, m); }
    if ((t & 63) == 0) { red[t >> 6] = sum; red[4 + (t >> 6)] = ssq; }
    __syncthreads();
    float tot  = red[0] + red[1] + red[2] + red[3];
    float totq = red[4] + red[5] + red[6] + red[7];
    float mean = tot * (1.f / (float)D_);
    float var  = totq * (1.f / (float)D_) - mean * mean;
    float inv  = rsqrtf(var + EPS_);
    float o[8];
#pragma unroll
    for (int i = 0; i < 8; ++i) {
        int c = t * 8 + i;
        float v = (a[i] - mean) * inv;
        o[i] = (1.f + mv[D_ + c]) * v + mv[c];
    }
    uint4 pk;
    pk.x = pack2(o[0], o[1]); pk.y = pack2(o[2], o[3]);
    pk.z = pack2(o[4], o[5]); pk.w = pack2(o[6], o[7]);
    *(uint4*)(xm + (size_t)s * D_ + t * 8) = pk;
}

// ---------------- kernel 3a: 8-wave 256x256 bf16 MFMA GEMM (QKV only), bf16 out -----------------
// r22/r24/r26/r28-exact config (measured best: ~93us, reproduced 4x). BK=64, LDS 2x64KB, ONE
// barrier per K-tile with vmcnt(0). Measured-regressed alternatives: BK=32 dbuf (r23, +10us),
// fused W-cvt 2-barrier (r25, +30us), counted-vmcnt depth-2 4-buffer (r29, +10-17us) — the
// barrier-count term dominates any in-flight-load gain without a full 8-phase interleave (m196).
__global__ __launch_bounds__(512, 2) void gemm8_bf16_kernel(
    const unsigned short* __restrict__ A,
    const unsigned short* __restrict__ Wx, const float* __restrict__ bx,
    const unsigned short* __restrict__ Wy, const float* __restrict__ by,
    unsigned short* __restrict__ C, int N)
{
    __shared__ __align__(16) unsigned short As[2][256 * 64];   // 2 x 32KB
    __shared__ __align__(16) unsigned short Bs[2][256 * 64];   // 2 x 32KB  (128KB total)
    int m0 = blockIdx.y * 256, n0 = blockIdx.x * 256;
    const unsigned short* W = (m0 < SX_) ? Wx : Wy;
    const float* bb = (m0 < SX_) ? bx : by;
    int t = threadIdx.x;                       // 0..511
    int wv = t >> 6, lane = t & 63, l31 = lane & 31, g = lane >> 5;
    int wr = wv >> 2, wc = wv & 3;             // 2 M-halves x 4 N-quarters
    int off[4];
#pragma unroll
    for (int i = 0; i < 4; ++i) {
        int c = i * 512 + t, r = c >> 3, sl = c & 7;
        off[i] = r * D_ + ((sl ^ (r & 7)) * 8);
    }
    const unsigned short* gA = A + (size_t)m0 * D_;
    const unsigned short* gW = W + (size_t)n0 * D_;
    int dstw = wv * 512;                       // shorts; instr i adds i*4096; lane*16B by HW
    f32x16 acc[4][2];
#pragma unroll
    for (int i = 0; i < 4; ++i)
#pragma unroll
        for (int j = 0; j < 2; ++j)
#pragma unroll
            for (int r = 0; r < 16; ++r) acc[i][j][r] = 0.f;
    int arow = wr * 128 + l31;                 // + i*32 : rows of A (B-operand of mfma)
    int brow = wc * 64 + l31;                  // + j*32 : rows of W (A-operand of mfma)
    int s7 = l31 & 7;

    // prologue: stage K-tile 0 into buffer 0 (8 loads/thread)
#pragma unroll
    for (int i = 0; i < 4; ++i) gload16(gA + off[i], &As[0][i * 4096 + dstw]);
#pragma unroll
    for (int i = 0; i < 4; ++i) gload16(gW + off[i], &Bs[0][i * 4096 + dstw]);

    const int NT = D_ / 64;                    // 32 K-tiles
    for (int kt = 0; kt < NT; ++kt) {
        int cur = kt & 1;
        asm volatile("s_waitcnt vmcnt(0)" ::: "memory");   // K-tile kt landed
        __builtin_amdgcn_s_barrier();          // all waves' loads landed; prev reads done
        if (kt + 1 < NT) {                     // prefetch K-tile kt+1 into the freed buffer
            int nb = cur ^ 1, k1 = (kt + 1) * 64;
#pragma unroll
            for (int i = 0; i < 4; ++i) gload16(gA + k1 + off[i], &As[nb][i * 4096 + dstw]);
#pragma unroll
            for (int i = 0; i < 4; ++i) gload16(gW + k1 + off[i], &Bs[nb][i * 4096 + dstw]);
        }
#pragma unroll
        for (int ks = 0; ks < 4; ++ks) {       // 4 k-slices of 16
            int sx = ((ks * 2 + g) ^ s7) * 8;
            short8 af[4], bf[2];
#pragma unroll
            for (int i = 0; i < 4; ++i)
                af[i] = *(const short8*)&As[cur][(arow + i * 32) * 64 + sx];
#pragma unroll
            for (int j = 0; j < 2; ++j)
                bf[j] = *(const short8*)&Bs[cur][(brow + j * 32) * 64 + sx];
#pragma unroll
            for (int i = 0; i < 4; ++i)
#pragma unroll
                for (int j = 0; j < 2; ++j)
                    acc[i][j] = __builtin_amdgcn_mfma_f32_32x32x16_bf16(bf[j], af[i], acc[i][j], 0, 0, 0);
        }
    }

#pragma unroll
    for (int i = 0; i < 4; ++i) {
        int row = m0 + wr * 128 + i * 32 + l31;
#pragma unroll
        for (int j = 0; j < 2; ++j)
#pragma unroll
            for (int q = 0; q < 4; ++q) {
                int n = n0 + wc * 64 + j * 32 + q * 8 + 4 * g;
                float o0 = acc[i][j][q * 4 + 0] + bb[n + 0];
                float o1 = acc[i][j][q * 4 + 1] + bb[n + 1];
                float o2 = acc[i][j][q * 4 + 2] + bb[n + 2];
                float o3 = acc[i][j][q * 4 + 3] + bb[n + 3];
                *(uint2*)(C + (size_t)row * N + n) = make_uint2(pack2(o0, o1), pack2(o2, o3));
            }
    }
}

// ---------------- kernel 3b: 2-phase 128x128 GEMM (out-proj, f32+gate+residual epilogue) --------
__global__ __launch_bounds__(256) void gemm_bf16_kernel(
    const unsigned short* __restrict__ A,
    const unsigned short* __restrict__ Wx, const float* __restrict__ bx,
    const unsigned short* __restrict__ Wy, const float* __restrict__ by,
    void* __restrict__ Cout, int N,
    const float* __restrict__ gx, const float* __restrict__ gy,
    const float* __restrict__ rx, const float* __restrict__ ry,
    int mode)
{
    __shared__ __align__(16) unsigned short As[2][128 * 32];
    __shared__ __align__(16) unsigned short Bs[2][128 * 32];
    int m0 = blockIdx.y * 128, n0 = blockIdx.x * 128;
    const unsigned short* W = (m0 < SX_) ? Wx : Wy;
    const float* bb = (m0 < SX_) ? bx : by;
    int t = threadIdx.x;
    int wv = t >> 6, lane = t & 63, l31 = lane & 31, g = lane >> 5;
    int wr = wv >> 1, wc = wv & 1;
    int srow = t >> 2, ssl = t & 3;
    const unsigned short* gA = A + (size_t)(m0 + srow) * D_ + ((ssl ^ ((srow >> 1) & 3)) * 8);
    const unsigned short* gW = W + (size_t)(n0 + srow) * D_ + ((ssl ^ ((srow >> 1) & 3)) * 8);
    f32x16 acc[2][2];
#pragma unroll
    for (int i = 0; i < 2; ++i)
#pragma unroll
        for (int j = 0; j < 2; ++j)
#pragma unroll
            for (int r = 0; r < 16; ++r) acc[i][j][r] = 0.f;
    int arow = wr * 64 + l31;
    int wrow = wc * 64 + l31;
    int a3 = (arow >> 1) & 3, w3 = (wrow >> 1) & 3;

    gload16(gA,            &As[0][wv * 512]);
    gload16(gA + 64 * D_,  &As[0][2048 + wv * 512]);
    gload16(gW,            &Bs[0][wv * 512]);
    gload16(gW + 64 * D_,  &Bs[0][2048 + wv * 512]);
    __syncthreads();

    for (int k0 = 0; k0 < D_; k0 += 32) {
        int cur = (k0 >> 5) & 1;
        if (k0 + 32 < D_) {
            int nb = cur ^ 1;
            gload16(gA + k0 + 32,           &As[nb][wv * 512]);
            gload16(gA + 64 * D_ + k0 + 32, &As[nb][2048 + wv * 512]);
            gload16(gW + k0 + 32,           &Bs[nb][wv * 512]);
            gload16(gW + 64 * D_ + k0 + 32, &Bs[nb][2048 + wv * 512]);
        }
#pragma unroll
        for (int kk = 0; kk < 2; ++kk) {
            int slot = kk * 2 + g;
            short8 af[2], wf[2];
#pragma unroll
            for (int i = 0; i < 2; ++i) {
                af[i] = *(const short8*)&As[cur][(arow + i * 32) * 32 + ((slot ^ a3) * 8)];
                wf[i] = *(const short8*)&Bs[cur][(wrow + i * 32) * 32 + ((slot ^ w3) * 8)];
            }
#pragma unroll
            for (int i = 0; i < 2; ++i)
#pragma unroll
                for (int j = 0; j < 2; ++j)
                    acc[i][j] = __builtin_amdgcn_mfma_f32_32x32x16_bf16(wf[j], af[i], acc[i][j], 0, 0, 0);
        }
        __syncthreads();
    }

#pragma unroll
    for (int i = 0; i < 2; ++i) {
        int row = m0 + wr * 64 + i * 32 + l31;
        if (mode == 0) {
            unsigned short* C = (unsigned short*)Cout;
#pragma unroll
            for (int j = 0; j < 2; ++j)
#pragma unroll
                for (int q = 0; q < 4; ++q) {
                    int n = n0 + wc * 64 + j * 32 + q * 8 + 4 * g;
                    float o0 = acc[i][j][q * 4 + 0] + bb[n + 0];
                    float o1 = acc[i][j][q * 4 + 1] + bb[n + 1];
                    float o2 = acc[i][j][q * 4 + 2] + bb[n + 2];
                    float o3 = acc[i][j][q * 4 + 3] + bb[n + 3];
                    *(uint2*)(C + (size_t)row * N + n) = make_uint2(pack2(o0, o1), pack2(o2, o3));
                }
        } else {
            float* C = (float*)Cout;
            const float* gt = (row < SX_) ? gx : gy;
            const float* rr = (row < SX_) ? rx + (size_t)row * N : ry + (size_t)(row - SX_) * N;
#pragma unroll
            for (int j = 0; j < 2; ++j)
#pragma unroll
                for (int q = 0; q < 4; ++q) {
                    int n = n0 + wc * 64 + j * 32 + q * 8 + 4 * g;
                    float4 o;
                    o.x = (acc[i][j][q * 4 + 0] + bb[n + 0]) * gt[n + 0] + rr[n + 0];
                    o.y = (acc[i][j][q * 4 + 1] + bb[n + 1]) * gt[n + 1] + rr[n + 1];
                    o.z = (acc[i][j][q * 4 + 2] + bb[n + 2]) * gt[n + 2] + rr[n + 2];
                    o.w = (acc[i][j][q * 4 + 3] + bb[n + 3]) * gt[n + 3] + rr[n + 3];
                    *(float4*)(C + (size_t)row * N + n) = o;
                }
        }
    }
}

// ---------------- kernel 4+4b FUSED: RMS+RoPE blocks ++ V-transpose blocks ----------------------
__global__ __launch_bounds__(256) void qkvt_vtrans_kernel(
    const unsigned short* __restrict__ qkvb,
    const float* __restrict__ fx, const float* __restrict__ fy,
    const float* __restrict__ wq, const float* __restrict__ wk,
    unsigned short* __restrict__ qh, unsigned short* __restrict__ kh,
    unsigned short* __restrict__ vt, int nqkvt)
{
    __shared__ __align__(16) unsigned short T[64][72];
    int bid = blockIdx.x, t = threadIdx.x;
    if (bid < nqkvt) {
        int gid = bid * 4 + (t >> 6);
        int lane = t & 63;
        int s = gid >> 4;
        int h = gid & 15;
        const unsigned short* base = qkvb + (size_t)s * NQKV_ + h * HD_;
        int d = lane * 2;
        unsigned qu = *(const unsigned*)(base + d);
        unsigned ku = *(const unsigned*)(base + 2048 + d);
        float qx = bf2f_lo(qu), qy = bf2f_hi(qu);
        float kx = bf2f_lo(ku), ky = bf2f_hi(ku);
        float sq = qx * qx + qy * qy;
        float sk = kx * kx + ky * ky;
#pragma unroll
        for (int m = 32; m >= 1; m >>= 1) { sq += __shfl_xor(sq, m); sk += __shfl_xor(sk, m); }
        float qs = rsqrtf(sq * (1.f / 128.f) + EPS_) * ATTN_SCALE_L2E;
        float ks = rsqrtf(sk * (1.f / 128.f) + EPS_);
        float q0 = qx * qs * wq[d], q1 = qy * qs * wq[d + 1];
        float k0 = kx * ks * wk[d], k1 = ky * ks * wk[d + 1];
        if (lane < 32) {
            const float* f = (s < SX_) ? fx + (size_t)s * DR_ + d
                                       : fy + (size_t)(s - SX_) * DR_ + d;
            float cs = f[0], sn = f[1];
            float o0 = q0 * cs - q1 * sn, o1 = q0 * sn + q1 * cs;
            q0 = o0; q1 = o1;
            o0 = k0 * cs - k1 * sn; o1 = k0 * sn + k1 * cs;
            k0 = o0; k1 = o1;
        }
        size_t off = ((size_t)h * SZ_ + s) * HD_ + d;
        *(unsigned*)(qh + off) = pack2(q0, q1);
        *(unsigned*)(kh + off) = pack2(k0, k1);
    } else {
        int lid = bid - nqkvt;
        int s0 = (lid % 40) * 64;
        int d0 = ((lid / 40) & 1) * 64;
        int h  = lid / 80;
        int r = t >> 2, c = (t & 3) * 16;
        const unsigned short* src = qkvb + (size_t)(s0 + r) * NQKV_ + 4096 + h * HD_ + d0 + c;
        *(short8*)&T[r][c]     = *(const short8*)(src);
        *(short8*)&T[r][c + 8] = *(const short8*)(src + 8);
        __syncthreads();
        unsigned short o16[16];
#pragma unroll
        for (int i = 0; i < 16; ++i) o16[i] = T[c + i][r];
        unsigned short* dst = vt + ((size_t)h * HD_ + d0 + r) * SZ_ + s0 + c;
        *(short8*)dst       = *(short8*)&o16[0];
        *(short8*)(dst + 8) = *(short8*)&o16[8];
    }
}

// ---------------- kernel 5: bf16 MFMA flash attention, KV-split + dbuf gload_lds + T1 ------------
__global__ __launch_bounds__(256) void attn_mfma_kernel(
    const unsigned short* __restrict__ qh, const unsigned short* __restrict__ kh,
    const unsigned short* __restrict__ vt,
    unsigned short* __restrict__ Opart, float* __restrict__ mpart, float* __restrict__ lpart)
{
    __shared__ __align__(16) short Ks[2][64 * 128];   // [key][d], 256B rows, slot swizzled
    __shared__ __align__(16) short Vs[2][128 * 64];   // [d][key], 128B rows, slot swizzled
    int hw = (blockIdx.z * gridDim.y + blockIdx.y) * gridDim.x + blockIdx.x;
    int lg = xcd_swz(hw, QT_ * H_ * NS_);             // 1280 % 8 == 0
    int qt    = lg % QT_;
    int hs    = lg / QT_;
    int h     = hs % H_;
    int split = hs / H_;
    int t = threadIdx.x;
    int wv = t >> 6, lane = t & 63;
    int l31 = lane & 31, g = lane >> 5;
    int bq = qt * 128 + wv * 32;
    const unsigned short* kbase = kh + (size_t)h * SZ_ * HD_;
    const unsigned short* vbase = vt + (size_t)h * HD_ * SZ_;

    int koff[4], voff[4];
#pragma unroll
    for (int i = 0; i < 4; ++i) {
        int idx = i * 256 + t;
        int r = idx >> 4, sl = idx & 15;
        koff[i] = r * HD_ + (((sl & 8) | ((sl ^ (r & 7)) & 7)) * 8);
        int r2 = idx >> 3, sl2 = idx & 7;
        voff[i] = r2 * SZ_ + ((sl2 ^ (r2 & 7)) * 8);
    }
    int ldsOff = wv * 512;

    short8 qf[8];
    {
        const unsigned short* qb = qh + ((size_t)h * SZ_ + bq + l31) * HD_ + g * 8;
#pragma unroll
        for (int s = 0; s < 8; ++s) qf[s] = *(const short8*)(qb + s * 16);
    }

    f32x16 o[4];
#pragma unroll
    for (int db = 0; db < 4; ++db)
#pragma unroll
        for (int r = 0; r < 16; ++r) o[db][r] = 0.f;
    float mreg = -INFINITY, lreg = 0.f;
    bool qY = (bq >= SX_);
    int sw7 = l31 & 7;
    int ts0 = split * SPL_;
    const int NT = SPL_ / 64;   // 10

#pragma unroll
    for (int i = 0; i < 4; ++i)
        gload16(kbase + (size_t)ts0 * HD_ + koff[i], (unsigned short*)&Ks[0][0] + i * 2048 + ldsOff);
#pragma unroll
    for (int i = 0; i < 4; ++i)
        gload16(vbase + ts0 + voff[i], (unsigned short*)&Vs[0][0] + i * 2048 + ldsOff);
    __syncthreads();

    for (int it = 0; it < NT; ++it) {
        int t0 = ts0 + it * 64;
        int cur = it & 1;
        if (it + 1 < NT) {
            int nb = cur ^ 1;
            const unsigned short* kn = kbase + (size_t)(t0 + 64) * HD_;
            const unsigned short* vn = vbase + (t0 + 64);
#pragma unroll
            for (int i = 0; i < 4; ++i)
                gload16(kn + koff[i], (unsigned short*)&Ks[nb][0] + i * 2048 + ldsOff);
#pragma unroll
            for (int i = 0; i < 4; ++i)
                gload16(vn + voff[i], (unsigned short*)&Vs[nb][0] + i * 2048 + ldsOff);
        }

        bool same = (qY == (t0 >= SX_));
        f32x16 sc0, sc1;
#pragma unroll
        for (int r = 0; r < 16; ++r) { sc0[r] = 0.f; sc1[r] = 0.f; }
        const short* Krow0 = &Ks[cur][0] + l31 * 128;
        const short* Krow1 = &Ks[cur][0] + (l31 + 32) * 128;
        __builtin_amdgcn_s_setprio(1);
#pragma unroll
        for (int s = 4; s < 8; ++s) {
            int slot = 2 * s + g;
            int sl = (slot & 8) | ((slot ^ sw7) & 7);
            sc0 = __builtin_amdgcn_mfma_f32_32x32x16_bf16(*(const short8*)(Krow0 + sl * 8), qf[s], sc0, 0, 0, 0);
            sc1 = __builtin_amdgcn_mfma_f32_32x32x16_bf16(*(const short8*)(Krow1 + sl * 8), qf[s], sc1, 0, 0, 0);
        }
        if (same) {
#pragma unroll
            for (int s = 0; s < 4; ++s) {
                int slot = 2 * s + g;
                int sl = (slot & 8) | ((slot ^ sw7) & 7);
                sc0 = __builtin_amdgcn_mfma_f32_32x32x16_bf16(*(const short8*)(Krow0 + sl * 8), qf[s], sc0, 0, 0, 0);
                sc1 = __builtin_amdgcn_mfma_f32_32x32x16_bf16(*(const short8*)(Krow1 + sl * 8), qf[s], sc1, 0, 0, 0);
            }
        }
        __builtin_amdgcn_s_setprio(0);

        // ---- balanced-tree max (depth 6) ----
        float mx8[8];
#pragma unroll
        for (int r = 0; r < 8; ++r)
            mx8[r] = fmaxf(fmaxf(sc0[r], sc0[r + 8]), fmaxf(sc1[r], sc1[r + 8]));
        float mx40 = fmaxf(mx8[0], mx8[4]), mx41 = fmaxf(mx8[1], mx8[5]);
        float mx42 = fmaxf(mx8[2], mx8[6]), mx43 = fmaxf(mx8[3], mx8[7]);
        float pm = fmaxf(fmaxf(mx40, mx41), fmaxf(mx42, mx43));
        pm = fmaxf(pm, __shfl_xor(pm, 32));
        float mnew = fmaxf(mreg, pm);
        float corr = fexp2(mreg - mnew);       // raw v_exp_f32
        mreg = mnew;
        float pp0[16], pp1[16];
#pragma unroll
        for (int r = 0; r < 16; ++r) {
            pp0[r] = fexp2(sc0[r] - mnew);
            pp1[r] = fexp2(sc1[r] - mnew);
        }
        // ---- balanced-tree sum (depth 6) ----
        float s8[8];
#pragma unroll
        for (int r = 0; r < 8; ++r)
            s8[r] = (pp0[r] + pp0[r + 8]) + (pp1[r] + pp1[r + 8]);
        float s40 = s8[0] + s8[4], s41 = s8[1] + s8[5];
        float s42 = s8[2] + s8[6], s43 = s8[3] + s8[7];
        float rs = (s40 + s41) + (s42 + s43);
        rs += __shfl_xor(rs, 32);
        lreg = lreg * corr + rs;
#pragma unroll
        for (int db = 0; db < 4; ++db)
#pragma unroll
            for (int r = 0; r < 16; ++r) o[db][r] *= corr;

        short8 pa0 = mkfrag(&pp0[0]), pa1 = mkfrag(&pp0[8]);
        short8 pa2 = mkfrag(&pp1[0]), pa3 = mkfrag(&pp1[8]);
        const short* Vb = &Vs[cur][0];
        __builtin_amdgcn_s_setprio(1);
#pragma unroll
        for (int ks = 0; ks < 4; ++ks) {
            short8 pf = (ks == 0) ? pa0 : (ks == 1) ? pa1 : (ks == 2) ? pa2 : pa3;
#pragma unroll
            for (int db = 0; db < 4; ++db) {
                int row = db * 32 + l31;
                int sl = (2 * ks + g) ^ (l31 & 7);
                const short8 vf = *(const short8*)(Vb + row * 64 + sl * 8);
                o[db] = __builtin_amdgcn_mfma_f32_32x32x16_bf16(vf, pf, o[db], 0, 0, 0);
            }
        }
        __builtin_amdgcn_s_setprio(0);
        __syncthreads();
    }

    // write unnormalized partial — acc regs q*4..q*4+3 map to contiguous d (C/D layout),
    // so pack 4 bf16 into one uint2 store.
    int basep = ((split * QT_ + qt) * H_ + h) * 128 + wv * 32 + l31;
    unsigned short* op = Opart + (size_t)basep * 128;
#pragma unroll
    for (int db = 0; db < 4; ++db)
#pragma unroll
        for (int q = 0; q < 4; ++q) {
            int d = db * 32 + q * 8 + 4 * g;
            *(uint2*)(op + d) = make_uint2(
                pack2(o[db][q * 4 + 0], o[db][q * 4 + 1]),
                pack2(o[db][q * 4 + 2], o[db][q * 4 + 3]));
        }
    if (g == 0) { mpart[basep] = mreg; lpart[basep] = lreg; }
}

// ---------------- kernel 5b: combine NS_ partials -> bf16 z (m in log2 domain) ------------------
__global__ __launch_bounds__(256) void attn_combine_kernel(
    const unsigned short* __restrict__ Opart,
    const float* __restrict__ mpart, const float* __restrict__ lpart,
    unsigned short* __restrict__ z)
{
    int t = threadIdx.x;
    int gid = blockIdx.x * 4 + (t >> 6);
    int lane = t & 63;
    int h = gid & 15;
    int r = gid >> 4;
    int qtile = r >> 7, qi = r & 127;
    int pidx[NS_];
    float m[NS_];
    float mx = -INFINITY;
#pragma unroll
    for (int s = 0; s < NS_; ++s) {
        pidx[s] = ((s * QT_ + qtile) * H_ + h) * 128 + qi;
        m[s] = mpart[pidx[s]];
        mx = fmaxf(mx, m[s]);
    }
    float L = 0.f;
    float w[NS_];
#pragma unroll
    for (int s = 0; s < NS_; ++s) {
        w[s] = fexp2(m[s] - mx);               // log2 domain, raw v_exp_f32
        L += w[s] * lpart[pidx[s]];
    }
    float invL = 1.f / L;
    int d = lane * 2;
    float a0 = 0.f, a1 = 0.f;
#pragma unroll
    for (int s = 0; s < NS_; ++s) {
        unsigned u = *(const unsigned*)(Opart + (size_t)pidx[s] * 128 + d);
        a0 += w[s] * bf2f_lo(u);
        a1 += w[s] * bf2f_hi(u);
    }
    *(unsigned*)(z + (size_t)r * D_ + h * HD_ + d) = pack2(a0 * invL, a1 * invL);
}

extern "C" void kernel_launch(void* const* d_in, const int* in_sizes, int n_in,
                              void* d_out, int out_size, void* d_ws, size_t ws_size,
                              hipStream_t stream) {
    const float* x    = (const float*)d_in[0];
    const float* y    = (const float*)d_in[1];
    const float* mod  = (const float*)d_in[2];
    const float* fx   = (const float*)d_in[3];
    const float* fy   = (const float*)d_in[4];
    const float* Wqx  = (const float*)d_in[7];
    const float* bqx  = (const float*)d_in[8];
    const float* Wqy  = (const float*)d_in[9];
    const float* bqy  = (const float*)d_in[10];
    const float* Wout = (const float*)d_in[11];
    const float* bout = (const float*)d_in[12];
    const float* wq   = (const float*)d_in[13];
    const float* wk   = (const float*)d_in[14];
    const float* Wmq  = (const float*)d_in[15];
    const float* bmq  = (const float*)d_in[16];
    const float* Wmk  = (const float*)d_in[17];
    const float* bmk  = (const float*)d_in[18];

    // workspace layout — total ≈ 142.8 MB (vh slot unused, layout kept stable)
    float* mq   = (float*)d_ws;                              // 6144
    float* mkv  = mq + NQKV_;                                // 6144
    unsigned short* xm   = (unsigned short*)(mkv + NQKV_);   // SZ*D bf16 (later: z)
    unsigned short* qkvb = xm + (size_t)SZ_ * D_;            // SZ*6144 bf16 (later: m/l partials)
    unsigned short* qh   = qkvb + (size_t)SZ_ * NQKV_;       // H*SZ*HD bf16 each
    unsigned short* kh   = qh + (size_t)H_ * SZ_ * HD_;
    unsigned short* vh   = kh + (size_t)H_ * SZ_ * HD_;      // (unused)
    unsigned short* vt   = vh + (size_t)H_ * SZ_ * HD_;
    unsigned short* wqxb = vt + (size_t)H_ * SZ_ * HD_;      // 6144*2048 bf16 (later: O~ partials)
    unsigned short* wqyb = wqxb + (size_t)NQKV_ * D_;
    unsigned short* wob  = wqyb + (size_t)NQKV_ * D_;        // 2048*2048 bf16
    unsigned short* z    = xm;                               // alias: xm dead after QKV GEMM
    unsigned short* Opart = wqxb;
    float* mpart = (float*)qkvb;
    float* lpart = mpart + NS_ * QT_ * H_ * 128;
    float* out  = (float*)d_out;

    const int n1 = NQKV_ * D_, n3 = D_ * D_;
    const int ncvt = (2 * n1 + n3) / 2048;                   // 14336
    const int ngemv = 2 * NQKV_ / 4;                         // 3072
    hipLaunchKernelGGL(cvt_gemv_kernel, dim3(ncvt + ngemv), dim3(256), 0, stream,
                       Wqx, Wqy, Wout, wqxb, n1, n1, n3, ncvt,
                       mod, Wmq, bmq, Wmk, bmk, mq, mkv);
    hipLaunchKernelGGL(ln_mod_kernel, dim3(SZ_), dim3(256), 0, stream,
                       x, y, mq, mkv, xm);
    hipLaunchKernelGGL(gemm8_bf16_kernel, dim3(NQKV_ / 256, SZ_ / 256), dim3(512), 0, stream,
                       xm, wqxb, bqx, wqyb, bqy, qkvb, NQKV_);
    const int nqkvt = SZ_ * H_ / 4;                          // 10240
    const int nvt = (SZ_ / 64) * (HD_ / 64) * H_;            // 1280
    hipLaunchKernelGGL(qkvt_vtrans_kernel, dim3(nqkvt + nvt), dim3(256), 0, stream,
                       qkvb, fx, fy, wq, wk, qh, kh, vt, nqkvt);
    hipLaunchKernelGGL(attn_mfma_kernel, dim3(QT_, H_, NS_), dim3(256), 0, stream,
                       qh, kh, vt, Opart, mpart, lpart);
    hipLaunchKernelGGL(attn_combine_kernel, dim3(SZ_ * H_ / 4), dim3(256), 0, stream,
                       Opart, mpart, lpart, z);
    hipLaunchKernelGGL(gemm_bf16_kernel, dim3(D_ / 128, SZ_ / 128), dim3(256), 0, stream,
                       z, wob, bout, wob, bout, (void*)out, D_,
                       mq + 2 * D_, mkv + 2 * D_, x, y, 1);
}